// Round 13
// baseline (91.138 us; speedup 1.0000x reference)
//
#include <hip/hip_runtime.h>

namespace {
constexpr int kH = 192, kW = 640, kHW = kH * kW;
constexpr int kHW4 = kHW / 4;           // 30720 granules per plane
constexpr int kB = 2, kC = 64;          // batch, image channels
constexpr int kN0 = 40000, kC0 = 32;    // level0 points/channels
constexpr int kN1 = 20000, kC1 = 64;    // level1 points/channels
constexpr int kCL = 67;                 // C1 + 3
constexpr int kBHW = kB * kHW;
constexpr int kWin4 = 2 * kBHW / 4;
// k2 partition: scatter | precomp | gate(single-plane, 64 granules/block)
constexpr int kScatB = 469;   // ceil(120000/256)
constexpr int kGateB0 = 470;
constexpr int kGateB = kB * kHW4 / 64;  // 960
// katt tile: 8 rows x 16 cols, halo 10 x 18 -> 1920 blocks
constexpr int kTH = 8, kTW = 16;
constexpr int kTilesX = kW / kTW;           // 40
constexpr int kTilesY = kH / kTH;           // 24
constexpr int kTilesPB = kTilesX * kTilesY; // 960
constexpr int kHaloH = kTH + 2, kHaloW = kTW + 2;  // 10 x 18
constexpr int kHaloN = kHaloH * kHaloW;     // 180

typedef float vf4 __attribute__((ext_vector_type(4)));

// ---------------------------------------------------------------------------
// init: fill the two winner maps with -1.
// ---------------------------------------------------------------------------
__global__ __launch_bounds__(256) void kinit(int4* __restrict__ win4) {
  int i = blockIdx.x * 256 + threadIdx.x;
  if (i < kWin4) win4[i] = make_int4(-1, -1, -1, -1);
}

// ---------------------------------------------------------------------------
// K2 (heterogeneous, independent parts):
//  blocks [0,469): winner scatter (last-write-wins == max index wins)
//  block 469: LDS-staged fold: b'=W2@b0+b2; A1=Wsp^T@W2; M0=A1@W0;
//             sb_k=Wsp[:,k].b'; wsum_k=sum_c Wsp[c,k]
//  blocks [470,1430): gate -> SINGLE g plane. Block = 64 granules; 256 thr =
//   64 granules x 4 chunks of 16 ch; LDS-reduce the 4 partials (fixed order).
// ---------------------------------------------------------------------------
__global__ __launch_bounds__(256) void k2(
    const float* __restrict__ coor0, const float* __restrict__ coor1,
    int* __restrict__ win0, int* __restrict__ win1,
    const float* __restrict__ W0, const float* __restrict__ b0,
    const float* __restrict__ W2, const float* __restrict__ b2,
    const float* __restrict__ Wsp, float* __restrict__ M0,
    float* __restrict__ A1g, float* __restrict__ sb, float* __restrict__ wsum,
    const float* __restrict__ x_rgb, const float* __restrict__ W3,
    float* __restrict__ g) {
  __shared__ float W2s[kCL * kCL];
  __shared__ float W0s[kCL * 35];
  __shared__ float Wsps[kCL * 9];
  __shared__ float A1s[9 * kCL];
  __shared__ float bps[kCL];
  const int bid = blockIdx.x;
  const int t = threadIdx.x;
  if (bid >= kGateB0) {  // ---- gate ----
    __shared__ float4 part[4][64];
    const int gg = t & 63, q = t >> 6;
    const int gran = (bid - kGateB0) * 64 + gg;
    const int b = gran / kHW4;
    const int p4 = gran - b * kHW4;
    const float4* xr = (const float4*)(x_rgb + (size_t)b * kC * kHW) + p4;
    float4 acc = make_float4(0.f, 0.f, 0.f, 0.f);
#pragma unroll
    for (int cc = 0; cc < 16; ++cc) {
      const int c = q * 16 + cc;
      float wv = W3[c];
      float4 x4 = xr[(size_t)c * kHW4];
      acc.x += wv * x4.x;
      acc.y += wv * x4.y;
      acc.z += wv * x4.z;
      acc.w += wv * x4.w;
    }
    part[q][gg] = acc;
    __syncthreads();
    if (t < 64) {
      float4 p0 = part[0][t], p1 = part[1][t], p2 = part[2][t],
             p3 = part[3][t];
      float4 s;
      s.x = p0.x + p1.x + p2.x + p3.x;
      s.y = p0.y + p1.y + p2.y + p3.y;
      s.z = p0.z + p1.z + p2.z + p3.z;
      s.w = p0.w + p1.w + p2.w + p3.w;
      ((float4*)g)[(bid - kGateB0) * 64 + t] = s;
    }
    return;
  }
  if (bid < kScatB) {  // ---- scatter ----
    int idx = bid * 256 + t;
    const float* coor;
    int* win;
    int N;
    if (idx < kB * kN0) {
      coor = coor0; win = win0; N = kN0;
    } else {
      idx -= kB * kN0;
      if (idx >= kB * kN1) return;
      coor = coor1; win = win1; N = kN1;
    }
    int b = idx / N;
    float u = coor[(size_t)idx * 2 + 0];
    float v = coor[(size_t)idx * 2 + 1];
    u = fminf(fmaxf(u, 0.f), 1.f);
    v = fminf(fmaxf(v, 0.f), 1.f);
    int r = (int)(v * (float)kH);  // row from coor[:,1]
    int c = (int)(u * (float)kW);  // col from coor[:,0]
    if (r < kH && c < kW) {
      int n = idx - b * N;
      atomicMax(&win[b * kHW + r * kW + c], n);
    }
    return;
  }
  // ---- precomp (block 469, LDS-staged) ----
  for (int i = t; i < kCL * kCL; i += 256) W2s[i] = W2[i];
  for (int i = t; i < kCL * 35; i += 256) W0s[i] = W0[i];
  for (int i = t; i < kCL * 9; i += 256) Wsps[i] = Wsp[i];
  __syncthreads();
  if (t < kCL) {
    float s = b2[t];
    for (int j = 0; j < kCL; ++j) s += W2s[t * kCL + j] * b0[j];
    bps[t] = s;
  }
  for (int idx = t; idx < 9 * kCL; idx += 256) {
    int k = idx / kCL, j = idx - k * kCL;
    float s = 0.f;
    for (int c = 0; c < kCL; ++c) s += Wsps[c * 9 + k] * W2s[c * kCL + j];
    A1s[idx] = s;
    A1g[idx] = s;
  }
  __syncthreads();
  for (int idx = t; idx < 9 * 35; idx += 256) {
    int k = idx / 35, i = idx - k * 35;
    float s = 0.f;
    for (int j = 0; j < kCL; ++j) s += A1s[k * kCL + j] * W0s[j * 35 + i];
    M0[idx] = s;
  }
  if (t < 9) {
    float s = 0.f;
    for (int c = 0; c < kCL; ++c) s += Wsps[c * 9 + t] * bps[c];
    sb[t] = s;
  } else if (t >= 16 && t < 25) {
    int k = t - 16;
    float s = 0.f;
    for (int c = 0; c < kCL; ++c) s += Wsps[c * 9 + k];
    wsum[k] = s;
  }
}

// ---------------------------------------------------------------------------
// katt: one 8x16 tile per block (1920 blocks) -> att plane (1 MB).
// phase A (10x18 halo, 1 px/thread): per-pixel tap projection
//   gv = b3 + g[pix];  y[k] = wsum[k]*gv + sb[k] + gathers  -> ylds (6.5 KB)
//   (out-of-image -> 0 == padded-plane semantics)
// phase B: att[px] = sigmoid(bsp + sum_{r,d} ylds[3r+d][lh+r][lw+d])
// ---------------------------------------------------------------------------
__global__ __launch_bounds__(256) void katt(
    const float* __restrict__ g, const int* __restrict__ win0,
    const int* __restrict__ win1, const float* __restrict__ feat0,
    const float* __restrict__ vox0, const float* __restrict__ feat1,
    const float* __restrict__ vox1, const float* __restrict__ M0,
    const float* __restrict__ A1, const float* __restrict__ sb,
    const float* __restrict__ wsum, const float* __restrict__ b3,
    const float* __restrict__ bsp, float* __restrict__ att) {
  __shared__ float ylds[9][kHaloH][kHaloW];  // 6.48 KB
  const int t = threadIdx.x;
  const int tile = blockIdx.x;
  const int b = tile / kTilesPB;
  const int tr = tile - b * kTilesPB;
  const int ty = tr / kTilesX, tx = tr - ty * kTilesX;
  const int h0 = ty * kTH, w0 = tx * kTW;

  // ---- phase A ----
  if (t < kHaloN) {
    const int hh = t / kHaloW, ww = t - hh * kHaloW;
    const int h = h0 + hh - 1, w = w0 + ww - 1;
    float y[9];
    if (h < 0 || h >= kH || w < 0 || w >= kW) {
#pragma unroll
      for (int k = 0; k < 9; ++k) y[k] = 0.f;
    } else {
      const int pix = b * kHW + h * kW + w;
      const float gv = b3[0] + g[pix];
#pragma unroll
      for (int k = 0; k < 9; ++k) y[k] = wsum[k] * gv + sb[k];
      const int w0i = win0[pix];
      if (w0i >= 0) {
        const float4* f0 =
            (const float4*)(feat0 + ((size_t)b * kN0 + w0i) * kC0);
#pragma unroll
        for (int i4 = 0; i4 < 8; ++i4) {
          float4 v = f0[i4];
#pragma unroll
          for (int k = 0; k < 9; ++k) {
            const float* m = M0 + k * 35 + i4 * 4;
            y[k] += m[0] * v.x + m[1] * v.y + m[2] * v.z + m[3] * v.w;
          }
        }
        const float* v0 = vox0 + ((size_t)b * kN0 + w0i) * 3;
#pragma unroll
        for (int ii = 0; ii < 3; ++ii) {
          float v = v0[ii];
#pragma unroll
          for (int k = 0; k < 9; ++k) y[k] += M0[k * 35 + kC0 + ii] * v;
        }
      }
      const int w1i = win1[pix];
      if (w1i >= 0) {
        const float4* f1 =
            (const float4*)(feat1 + ((size_t)b * kN1 + w1i) * kC1);
#pragma unroll
        for (int i4 = 0; i4 < 16; ++i4) {
          float4 v = f1[i4];
#pragma unroll
          for (int k = 0; k < 9; ++k) {
            const float* m = A1 + k * kCL + i4 * 4;
            y[k] += m[0] * v.x + m[1] * v.y + m[2] * v.z + m[3] * v.w;
          }
        }
        const float* v1 = vox1 + ((size_t)b * kN1 + w1i) * 3;
#pragma unroll
        for (int ii = 0; ii < 3; ++ii) {
          float v = v1[ii];
#pragma unroll
          for (int k = 0; k < 9; ++k) y[k] += A1[k * kCL + kC1 + ii] * v;
        }
      }
    }
#pragma unroll
    for (int k = 0; k < 9; ++k) ylds[k][hh][ww] = y[k];
  }
  __syncthreads();

  // ---- phase B ----
  if (t < kTH * kTW) {
    const int lh = t / kTW, lw = t - lh * kTW;
    float logit = bsp[0];
#pragma unroll
    for (int r = 0; r < 3; ++r) {
#pragma unroll
      for (int d = 0; d < 3; ++d) logit += ylds[3 * r + d][lh + r][lw + d];
    }
    att[b * kHW + (h0 + lh) * kW + (w0 + lw)] =
        1.f / (1.f + __expf(-logit));
  }
}

// ---------------------------------------------------------------------------
// kmul: out[b,c,p] = x_rgb[b,c,p] * att[b,p] -- pure NT float4 stream.
// ---------------------------------------------------------------------------
__global__ __launch_bounds__(256) void kmul(const float* __restrict__ x_rgb,
                                            const float* __restrict__ att,
                                            float* __restrict__ out) {
  const int i = blockIdx.x * 256 + threadIdx.x;  // [0, B*C*kHW4)
  const int b = i / (kC * kHW4);
  const int r = i - b * (kC * kHW4);
  const int p4 = r % kHW4;
  float4 a4 = ((const float4*)att)[b * kHW4 + p4];
  vf4 x4 = __builtin_nontemporal_load((const vf4*)x_rgb + i);
  vf4 r4;
  r4.x = x4.x * a4.x;
  r4.y = x4.y * a4.y;
  r4.z = x4.z * a4.z;
  r4.w = x4.w * a4.w;
  __builtin_nontemporal_store(r4, (vf4*)out + i);
}

}  // namespace

extern "C" void kernel_launch(void* const* d_in, const int* in_sizes, int n_in,
                              void* d_out, int out_size, void* d_ws,
                              size_t ws_size, hipStream_t stream) {
  const float* x_rgb = (const float*)d_in[0];
  const float* feat0 = (const float*)d_in[1];
  const float* coor0 = (const float*)d_in[2];
  const float* vox0 = (const float*)d_in[3];
  const float* feat1 = (const float*)d_in[4];
  const float* coor1 = (const float*)d_in[5];
  const float* vox1 = (const float*)d_in[6];
  const float* W0 = (const float*)d_in[7];
  const float* b0 = (const float*)d_in[8];
  const float* W2 = (const float*)d_in[9];
  const float* b2 = (const float*)d_in[10];
  const float* W3 = (const float*)d_in[11];
  const float* b3 = (const float*)d_in[12];
  const float* Wsp = (const float*)d_in[13];
  const float* bsp = (const float*)d_in[14];
  float* out = (float*)d_out;

  // workspace: g[BHW] | att[BHW] | win0[BHW] | win1[BHW] | M0 | A1 | sb | wsum
  float* g = (float*)d_ws;
  float* att = g + (size_t)kBHW;
  int* win0 = (int*)(att + (size_t)kBHW);
  int* win1 = win0 + (size_t)kBHW;
  float* M0 = (float*)(win1 + (size_t)kBHW);
  float* A1 = M0 + 9 * 35;
  float* sb = A1 + 9 * kCL;
  float* wsum = sb + 9;

  kinit<<<(kWin4 + 255) / 256, 256, 0, stream>>>((int4*)win0);
  k2<<<kGateB0 + kGateB, 256, 0, stream>>>(coor0, coor1, win0, win1, W0, b0,
                                           W2, b2, Wsp, M0, A1, sb, wsum,
                                           x_rgb, W3, g);
  katt<<<kB * kTilesPB, 256, 0, stream>>>(g, win0, win1, feat0, vox0, feat1,
                                          vox1, M0, A1, sb, wsum, b3, bsp,
                                          att);
  kmul<<<kB * kC * kHW4 / 256, 256, 0, stream>>>(x_rgb, att, out);
}

// Round 15
// 75.549 us; speedup vs baseline: 1.2063x; 1.2063x over previous
//
#include <hip/hip_runtime.h>

namespace {
constexpr int kH = 192, kW = 640, kHW = kH * kW;
constexpr int kW4g = kW / 4;            // 160 granules per row
constexpr int kHW4 = kHW / 4;           // 30720 granules per plane
constexpr int kB = 2, kC = 64;          // batch, image channels
constexpr int kN0 = 40000, kC0 = 32;    // level0 points/channels
constexpr int kN1 = 20000, kC1 = 64;    // level1 points/channels
constexpr int kCL = 67;                 // C1 + 3
constexpr int kBHW = kB * kHW;
// zero-padded y planes: 18 = 9 taps x B, rows H+2, pitch W+8 (interior at +1,+4)
constexpr int kPH = kH + 2, kPW = kW + 8;  // 194 x 648
constexpr int kPW4 = kPW / 4;              // 162
constexpr int kPlane = kPH * kPW;          // 125712
constexpr int kYPF = 18 * kPlane;
constexpr int kWin4 = 2 * kBHW / 4;
// border float4s per plane: row0 (162) + row193 (162) + 192 rows x {col0,col161}
constexpr int kBord = 162 + 162 + 192 * 2;  // 708
constexpr int kBordTot = 18 * kBord;        // 12744
// K2 block partition
constexpr int kScatB = 469;   // ceil(120000/256) scatter blocks
constexpr int kGateB0 = 470;  // gate blocks start (469 = precomp)
constexpr int kGateB = kB * kHW4 * 4 / 256;  // 960
// kpass2 partition: 240 granule-chunks x 2 channel-halves
constexpr int kChunks = kB * kHW4 / 256;  // 240

typedef float vf4 __attribute__((ext_vector_type(4)));

// ---------------------------------------------------------------------------
// init: zero ONLY the padded-y borders (interior is fully rewritten by kgy
// each replay) and fill the two winner maps with -1.
// ---------------------------------------------------------------------------
__global__ __launch_bounds__(256) void kinit(float* __restrict__ yp,
                                             int4* __restrict__ win4) {
  int i = blockIdx.x * 256 + threadIdx.x;
  if (i < kBordTot) {
    int plane = i / kBord, r = i - plane * kBord;
    float4* base = (float4*)(yp + (size_t)plane * kPlane);
    int f4;
    if (r < 162) {
      f4 = r;                                  // row 0
    } else if (r < 324) {
      f4 = 193 * kPW4 + (r - 162);             // row 193
    } else {
      int rr = r - 324;
      int row = 1 + (rr >> 1);
      f4 = row * kPW4 + ((rr & 1) ? (kPW4 - 1) : 0);  // cols 0-3 / 644-647
    }
    base[f4] = make_float4(0.f, 0.f, 0.f, 0.f);
  } else {
    int j = i - kBordTot;
    if (j < kWin4) win4[j] = make_int4(-1, -1, -1, -1);
  }
}

// ---------------------------------------------------------------------------
// K2 (heterogeneous, all parts independent given win init):
//   blocks [0,469): winner-index scatter (last-write-wins == max index wins)
//   block  469    : LDS-staged fold of linear stages ->
//        b' = W2@b0+b2; A1 = Wsp^T@W2 [9,67]; M0 = A1@W0 [9,35];
//        sb_k = Wsp[:,k].b'; wsum_k = sum_c Wsp[c,k]
//   blocks [470,1430): gate partials
//        gpart[q][pix] = sum_{c in 16-chunk q} W3[c]*x_rgb[b,c,pix]
// ---------------------------------------------------------------------------
__global__ __launch_bounds__(256) void k2(
    const float* __restrict__ coor0, const float* __restrict__ coor1,
    int* __restrict__ win0, int* __restrict__ win1,
    const float* __restrict__ W0, const float* __restrict__ b0,
    const float* __restrict__ W2, const float* __restrict__ b2,
    const float* __restrict__ Wsp, float* __restrict__ M0,
    float* __restrict__ A1g, float* __restrict__ sb, float* __restrict__ wsum,
    const float* __restrict__ x_rgb, const float* __restrict__ W3,
    float* __restrict__ gpart) {
  __shared__ float W2s[kCL * kCL];
  __shared__ float W0s[kCL * 35];
  __shared__ float Wsps[kCL * 9];
  __shared__ float A1s[9 * kCL];
  __shared__ float bps[kCL];
  const int bid = blockIdx.x;
  if (bid >= kGateB0) {  // ---- gate ----
    const int j = (bid - kGateB0) * 256 + threadIdx.x;
    const int T = kB * kHW4;           // 61440 granules
    const int q = j / T;               // channel chunk 0..3 (uniform/block)
    const int gran = j - q * T;
    const int b = gran / kHW4;
    const int p4 = gran - b * kHW4;
    const float4* xr = (const float4*)(x_rgb + (size_t)b * kC * kHW) + p4;
    float4 acc = make_float4(0.f, 0.f, 0.f, 0.f);
#pragma unroll
    for (int cc = 0; cc < 16; ++cc) {
      const int c = q * 16 + cc;
      float wv = W3[c];
      float4 x4 = xr[(size_t)c * kHW4];
      acc.x += wv * x4.x;
      acc.y += wv * x4.y;
      acc.z += wv * x4.z;
      acc.w += wv * x4.w;
    }
    ((float4*)gpart)[j] = acc;
    return;
  }
  if (bid < kScatB) {  // ---- scatter ----
    int idx = bid * 256 + threadIdx.x;
    const float* coor;
    int* win;
    int N;
    if (idx < kB * kN0) {
      coor = coor0; win = win0; N = kN0;
    } else {
      idx -= kB * kN0;
      if (idx >= kB * kN1) return;
      coor = coor1; win = win1; N = kN1;
    }
    int b = idx / N;
    float u = coor[(size_t)idx * 2 + 0];
    float v = coor[(size_t)idx * 2 + 1];
    u = fminf(fmaxf(u, 0.f), 1.f);
    v = fminf(fmaxf(v, 0.f), 1.f);
    int r = (int)(v * (float)kH);  // row from coor[:,1]
    int c = (int)(u * (float)kW);  // col from coor[:,0]
    if (r < kH && c < kW) {
      int n = idx - b * N;
      atomicMax(&win[b * kHW + r * kW + c], n);
    }
    return;
  }
  // ---- precomp (block 469, LDS-staged) ----
  const int t = threadIdx.x;
  for (int i = t; i < kCL * kCL; i += 256) W2s[i] = W2[i];
  for (int i = t; i < kCL * 35; i += 256) W0s[i] = W0[i];
  for (int i = t; i < kCL * 9; i += 256) Wsps[i] = Wsp[i];
  __syncthreads();
  if (t < kCL) {
    float s = b2[t];
    for (int j = 0; j < kCL; ++j) s += W2s[t * kCL + j] * b0[j];
    bps[t] = s;
  }
  for (int idx = t; idx < 9 * kCL; idx += 256) {
    int k = idx / kCL, j = idx - k * kCL;
    float s = 0.f;
    for (int c = 0; c < kCL; ++c) s += Wsps[c * 9 + k] * W2s[c * kCL + j];
    A1s[idx] = s;
    A1g[idx] = s;
  }
  __syncthreads();
  for (int idx = t; idx < 9 * 35; idx += 256) {
    int k = idx / 35, i = idx - k * 35;
    float s = 0.f;
    for (int j = 0; j < kCL; ++j) s += A1s[k * kCL + j] * W0s[j * 35 + i];
    M0[idx] = s;
  }
  if (t < 9) {
    float s = 0.f;
    for (int c = 0; c < kCL; ++c) s += Wsps[c * 9 + t] * bps[c];
    sb[t] = s;
  } else if (t >= 16 && t < 25) {
    int k = t - 16;
    float s = 0.f;
    for (int c = 0; c < kCL; ++c) s += Wsps[c * 9 + k];
    wsum[k] = s;
  }
}

// ---------------------------------------------------------------------------
// kgy (v2 fixed): 3-way tap-split, weights staged in LDS.
// Stage this block's 3 taps of M0/A1 (+sb,wsum) into LDS with a strided loop
// (312 elements, 256 threads -- r14's bug was single-pass staging that left
// elements 256..311 unwritten). Inner loops then use broadcast ds_read.
// ---------------------------------------------------------------------------
__global__ __launch_bounds__(256) void kgy(
    const float* __restrict__ gpart, const int* __restrict__ win0,
    const int* __restrict__ win1, const float* __restrict__ feat0,
    const float* __restrict__ vox0, const float* __restrict__ feat1,
    const float* __restrict__ vox1, const float* __restrict__ M0,
    const float* __restrict__ A1, const float* __restrict__ sb,
    const float* __restrict__ wsum, const float* __restrict__ b3,
    float* __restrict__ yp) {
  __shared__ float M0s[3][36];   // 3 taps x 35 (pad 36)
  __shared__ float A1s[3][68];   // 3 taps x 67 (pad 68)
  __shared__ float sbs[3], wss[3];
  const int blk = blockIdx.x;
  const int tg = blk % 3;              // tap row group: taps 3tg..3tg+2
  const int t = threadIdx.x;
  // stage weights: 105 + 201 + 3 + 3 = 312 elements, strided over 256 threads
  for (int i = t; i < 312; i += 256) {
    if (i < 105) {
      int kk = i / 35, j = i - kk * 35;
      M0s[kk][j] = M0[(3 * tg + kk) * 35 + j];
    } else if (i < 306) {
      int r = i - 105;
      int kk = r / 67, j = r - kk * 67;
      A1s[kk][j] = A1[(3 * tg + kk) * kCL + j];
    } else if (i < 309) {
      sbs[i - 306] = sb[3 * tg + (i - 306)];
    } else {
      wss[i - 309] = wsum[3 * tg + (i - 309)];
    }
  }
  __syncthreads();

  const int pix = (blk / 3) * 256 + t;
  const int b = pix / kHW;
  const int pp = pix - b * kHW;
  const int h = pp / kW;
  const int w = pp - h * kW;
  const float gv = b3[0] + gpart[pix] + gpart[kBHW + pix] +
                   gpart[2 * kBHW + pix] + gpart[3 * kBHW + pix];
  float y[3];
#pragma unroll
  for (int kk = 0; kk < 3; ++kk) y[kk] = wss[kk] * gv + sbs[kk];

  const int w0 = win0[pix];
  if (w0 >= 0) {
    const float4* f0 = (const float4*)(feat0 + ((size_t)b * kN0 + w0) * kC0);
#pragma unroll
    for (int i4 = 0; i4 < 8; ++i4) {
      float4 v = f0[i4];
#pragma unroll
      for (int kk = 0; kk < 3; ++kk) {
        const float* m = &M0s[kk][i4 * 4];
        y[kk] += m[0] * v.x + m[1] * v.y + m[2] * v.z + m[3] * v.w;
      }
    }
    const float* v0 = vox0 + ((size_t)b * kN0 + w0) * 3;
#pragma unroll
    for (int i = 0; i < 3; ++i) {
      float v = v0[i];
#pragma unroll
      for (int kk = 0; kk < 3; ++kk) y[kk] += M0s[kk][kC0 + i] * v;
    }
  }
  const int w1 = win1[pix];
  if (w1 >= 0) {
    const float4* f1 = (const float4*)(feat1 + ((size_t)b * kN1 + w1) * kC1);
#pragma unroll
    for (int i4 = 0; i4 < 16; ++i4) {
      float4 v = f1[i4];
#pragma unroll
      for (int kk = 0; kk < 3; ++kk) {
        const float* m = &A1s[kk][i4 * 4];
        y[kk] += m[0] * v.x + m[1] * v.y + m[2] * v.z + m[3] * v.w;
      }
    }
    const float* v1 = vox1 + ((size_t)b * kN1 + w1) * 3;
#pragma unroll
    for (int i = 0; i < 3; ++i) {
      float v = v1[i];
#pragma unroll
      for (int kk = 0; kk < 3; ++kk) y[kk] += A1s[kk][kC1 + i] * v;
    }
  }
#pragma unroll
  for (int kk = 0; kk < 3; ++kk) {
    yp[((size_t)((3 * tg + kk) * kB + b) * kPH + (h + 1)) * kPW + 4 + w] =
        y[kk];
  }
}

// ---------------------------------------------------------------------------
// fused stencil+sigmoid+multiply, att-in-register:
// block <-> (256-granule chunk, channel HALF). thread <-> granule.
// ---------------------------------------------------------------------------
__global__ __launch_bounds__(256) void kpass2(const float* __restrict__ x_rgb,
                                              const float* __restrict__ yp,
                                              const float* __restrict__ bsp,
                                              float* __restrict__ out) {
  const int bid = blockIdx.x;
  const int q = bid / kChunks;         // channel half 0..1 (uniform/block)
  const int chunk = bid - q * kChunks;
  const int gran = chunk * 256 + threadIdx.x;
  const int b = gran / kHW4;
  const int p4 = gran - b * kHW4;
  const int h = p4 / kW4g;
  const int w4 = p4 - h * kW4g;

  const float bias = bsp[0];
  float4 lg = make_float4(bias, bias, bias, bias);
#pragma unroll
  for (int r = 0; r < 3; ++r) {
    const size_t rowoff = ((size_t)h + r) * kPW + 4 * w4;
    const float* pA = yp + (size_t)((3 * r + 0) * kB + b) * kPlane + rowoff;
    const float* pB = yp + (size_t)((3 * r + 1) * kB + b) * kPlane + rowoff;
    const float* pC = yp + (size_t)((3 * r + 2) * kB + b) * kPlane + rowoff;
    float LA = pA[3];
    float4 a4 = *(const float4*)(pA + 4);
    float4 b4 = *(const float4*)(pB + 4);
    float4 c4 = *(const float4*)(pC + 4);
    float RC = pC[8];
    lg.x += LA + b4.x + c4.y;
    lg.y += a4.x + b4.y + c4.z;
    lg.z += a4.y + b4.z + c4.w;
    lg.w += a4.z + b4.w + RC;
  }
  float4 att;
  att.x = 1.f / (1.f + __expf(-lg.x));
  att.y = 1.f / (1.f + __expf(-lg.y));
  att.z = 1.f / (1.f + __expf(-lg.z));
  att.w = 1.f / (1.f + __expf(-lg.w));

  const vf4* xr = (const vf4*)(x_rgb + (size_t)b * kC * kHW) + p4;
  vf4* op = (vf4*)(out + (size_t)b * kC * kHW) + p4;
#pragma unroll
  for (int cc = 0; cc < 32; ++cc) {
    const int c = q * 32 + cc;
    vf4 x4 = __builtin_nontemporal_load(xr + (size_t)c * kHW4);
    vf4 r4;
    r4.x = x4.x * att.x;
    r4.y = x4.y * att.y;
    r4.z = x4.z * att.z;
    r4.w = x4.w * att.w;
    __builtin_nontemporal_store(r4, op + (size_t)c * kHW4);
  }
}

}  // namespace

extern "C" void kernel_launch(void* const* d_in, const int* in_sizes, int n_in,
                              void* d_out, int out_size, void* d_ws,
                              size_t ws_size, hipStream_t stream) {
  const float* x_rgb = (const float*)d_in[0];
  const float* feat0 = (const float*)d_in[1];
  const float* coor0 = (const float*)d_in[2];
  const float* vox0 = (const float*)d_in[3];
  const float* feat1 = (const float*)d_in[4];
  const float* coor1 = (const float*)d_in[5];
  const float* vox1 = (const float*)d_in[6];
  const float* W0 = (const float*)d_in[7];
  const float* b0 = (const float*)d_in[8];
  const float* W2 = (const float*)d_in[9];
  const float* b2 = (const float*)d_in[10];
  const float* W3 = (const float*)d_in[11];
  const float* b3 = (const float*)d_in[12];
  const float* Wsp = (const float*)d_in[13];
  const float* bsp = (const float*)d_in[14];
  float* out = (float*)d_out;

  // workspace: yp[18*194*648] | gpart[4*BHW] | win0[BHW] | win1[BHW] | mats
  float* yp = (float*)d_ws;
  float* gpart = yp + (size_t)kYPF;
  int* win0 = (int*)(gpart + (size_t)4 * kBHW);
  int* win1 = win0 + (size_t)kBHW;
  float* M0 = (float*)(win1 + (size_t)kBHW);
  float* A1 = M0 + 9 * 35;
  float* sb = A1 + 9 * kCL;
  float* wsum = sb + 9;

  const int ninit = kBordTot + kWin4;
  kinit<<<(ninit + 255) / 256, 256, 0, stream>>>(yp, (int4*)win0);
  k2<<<kGateB0 + kGateB, 256, 0, stream>>>(coor0, coor1, win0, win1, W0, b0,
                                           W2, b2, Wsp, M0, A1, sb, wsum,
                                           x_rgb, W3, gpart);
  kgy<<<3 * kBHW / 256, 256, 0, stream>>>(gpart, win0, win1, feat0, vox0,
                                          feat1, vox1, M0, A1, sb, wsum, b3,
                                          yp);
  kpass2<<<2 * kChunks, 256, 0, stream>>>(x_rgb, yp, bsp, out);
}

// Round 16
// 71.669 us; speedup vs baseline: 1.2717x; 1.0541x over previous
//
#include <hip/hip_runtime.h>

namespace {
constexpr int kH = 192, kW = 640, kHW = kH * kW;
constexpr int kW4g = kW / 4;            // 160 granules per row
constexpr int kHW4 = kHW / 4;           // 30720 granules per plane
constexpr int kB = 2, kC = 64;          // batch, image channels
constexpr int kN0 = 40000, kC0 = 32;    // level0 points/channels
constexpr int kN1 = 20000, kC1 = 64;    // level1 points/channels
constexpr int kCL = 67;                 // C1 + 3
constexpr int kBHW = kB * kHW;
// zero-padded y planes: 18 = 9 taps x B, rows H+2, pitch W+8 (interior at +1,+4)
constexpr int kPH = kH + 2, kPW = kW + 8;  // 194 x 648
constexpr int kPW4 = kPW / 4;              // 162
constexpr int kPlane = kPH * kPW;          // 125712
constexpr int kYPF = 18 * kPlane;
constexpr int kWin4 = 2 * kBHW / 4;
// border float4s per plane: row0 (162) + row193 (162) + 192 rows x {col0,col161}
constexpr int kBord = 162 + 162 + 192 * 2;  // 708
constexpr int kBordTot = 18 * kBord;        // 12744
// K2 block partition: scatter | precomp | gate (64 granules/block, single g)
constexpr int kScatB = 469;   // ceil(120000/256) scatter blocks
constexpr int kGateB0 = 470;
constexpr int kGateB = kB * kHW4 / 64;  // 960
// kpass2 partition: 240 granule-chunks x 2 channel-halves
constexpr int kChunks = kB * kHW4 / 256;  // 240

typedef float vf4 __attribute__((ext_vector_type(4)));

// ---------------------------------------------------------------------------
// init: zero ONLY the padded-y borders (interior is fully rewritten by kgy
// each replay) and fill the two winner maps with -1.
// ---------------------------------------------------------------------------
__global__ __launch_bounds__(256) void kinit(float* __restrict__ yp,
                                             int4* __restrict__ win4) {
  int i = blockIdx.x * 256 + threadIdx.x;
  if (i < kBordTot) {
    int plane = i / kBord, r = i - plane * kBord;
    float4* base = (float4*)(yp + (size_t)plane * kPlane);
    int f4;
    if (r < 162) {
      f4 = r;                                  // row 0
    } else if (r < 324) {
      f4 = 193 * kPW4 + (r - 162);             // row 193
    } else {
      int rr = r - 324;
      int row = 1 + (rr >> 1);
      f4 = row * kPW4 + ((rr & 1) ? (kPW4 - 1) : 0);  // cols 0-3 / 644-647
    }
    base[f4] = make_float4(0.f, 0.f, 0.f, 0.f);
  } else {
    int j = i - kBordTot;
    if (j < kWin4) win4[j] = make_int4(-1, -1, -1, -1);
  }
}

// ---------------------------------------------------------------------------
// K2 (heterogeneous, all parts independent given win init):
//   blocks [0,469): winner-index scatter (last-write-wins == max index wins)
//   block  469    : LDS-staged fold of linear stages ->
//        b' = W2@b0+b2; A1 = Wsp^T@W2 [9,67]; M0 = A1@W0 [9,35];
//        sb_k = Wsp[:,k].b'; wsum_k = sum_c Wsp[c,k]
//   blocks [470,1430): gate -> SINGLE summed g plane (4 MB instead of the
//        16 MB 4-plane gpart). Block = 64 granules; 256 thr = 64 granules x
//        4 chunks of 16 ch; LDS-reduce the 4 partials in fixed order.
// ---------------------------------------------------------------------------
__global__ __launch_bounds__(256) void k2(
    const float* __restrict__ coor0, const float* __restrict__ coor1,
    int* __restrict__ win0, int* __restrict__ win1,
    const float* __restrict__ W0, const float* __restrict__ b0,
    const float* __restrict__ W2, const float* __restrict__ b2,
    const float* __restrict__ Wsp, float* __restrict__ M0,
    float* __restrict__ A1g, float* __restrict__ sb, float* __restrict__ wsum,
    const float* __restrict__ x_rgb, const float* __restrict__ W3,
    float* __restrict__ g) {
  __shared__ float W2s[kCL * kCL];
  __shared__ float W0s[kCL * 35];
  __shared__ float Wsps[kCL * 9];
  __shared__ float A1s[9 * kCL];
  __shared__ float bps[kCL];
  const int bid = blockIdx.x;
  const int t = threadIdx.x;
  if (bid >= kGateB0) {  // ---- gate ----
    __shared__ float4 part[4][64];
    const int gg = t & 63, q = t >> 6;
    const int gran = (bid - kGateB0) * 64 + gg;
    const int b = gran / kHW4;
    const int p4 = gran - b * kHW4;
    const float4* xr = (const float4*)(x_rgb + (size_t)b * kC * kHW) + p4;
    float4 acc = make_float4(0.f, 0.f, 0.f, 0.f);
#pragma unroll
    for (int cc = 0; cc < 16; ++cc) {
      const int c = q * 16 + cc;
      float wv = W3[c];
      float4 x4 = xr[(size_t)c * kHW4];
      acc.x += wv * x4.x;
      acc.y += wv * x4.y;
      acc.z += wv * x4.z;
      acc.w += wv * x4.w;
    }
    part[q][gg] = acc;
    __syncthreads();
    if (t < 64) {
      float4 p0 = part[0][t], p1 = part[1][t], p2 = part[2][t],
             p3 = part[3][t];
      float4 s;
      s.x = p0.x + p1.x + p2.x + p3.x;
      s.y = p0.y + p1.y + p2.y + p3.y;
      s.z = p0.z + p1.z + p2.z + p3.z;
      s.w = p0.w + p1.w + p2.w + p3.w;
      ((float4*)g)[(bid - kGateB0) * 64 + t] = s;
    }
    return;
  }
  if (bid < kScatB) {  // ---- scatter ----
    int idx = bid * 256 + t;
    const float* coor;
    int* win;
    int N;
    if (idx < kB * kN0) {
      coor = coor0; win = win0; N = kN0;
    } else {
      idx -= kB * kN0;
      if (idx >= kB * kN1) return;
      coor = coor1; win = win1; N = kN1;
    }
    int b = idx / N;
    float u = coor[(size_t)idx * 2 + 0];
    float v = coor[(size_t)idx * 2 + 1];
    u = fminf(fmaxf(u, 0.f), 1.f);
    v = fminf(fmaxf(v, 0.f), 1.f);
    int r = (int)(v * (float)kH);  // row from coor[:,1]
    int c = (int)(u * (float)kW);  // col from coor[:,0]
    if (r < kH && c < kW) {
      int n = idx - b * N;
      atomicMax(&win[b * kHW + r * kW + c], n);
    }
    return;
  }
  // ---- precomp (block 469, LDS-staged) ----
  for (int i = t; i < kCL * kCL; i += 256) W2s[i] = W2[i];
  for (int i = t; i < kCL * 35; i += 256) W0s[i] = W0[i];
  for (int i = t; i < kCL * 9; i += 256) Wsps[i] = Wsp[i];
  __syncthreads();
  if (t < kCL) {
    float s = b2[t];
    for (int j = 0; j < kCL; ++j) s += W2s[t * kCL + j] * b0[j];
    bps[t] = s;
  }
  for (int idx = t; idx < 9 * kCL; idx += 256) {
    int k = idx / kCL, j = idx - k * kCL;
    float s = 0.f;
    for (int c = 0; c < kCL; ++c) s += Wsps[c * 9 + k] * W2s[c * kCL + j];
    A1s[idx] = s;
    A1g[idx] = s;
  }
  __syncthreads();
  for (int idx = t; idx < 9 * 35; idx += 256) {
    int k = idx / 35, i = idx - k * 35;
    float s = 0.f;
    for (int j = 0; j < kCL; ++j) s += A1s[k * kCL + j] * W0s[j * 35 + i];
    M0[idx] = s;
  }
  if (t < 9) {
    float s = 0.f;
    for (int c = 0; c < kCL; ++c) s += Wsps[c * 9 + t] * bps[c];
    sb[t] = s;
  } else if (t >= 16 && t < 25) {
    int k = t - 16;
    float s = 0.f;
    for (int c = 0; c < kCL; ++c) s += Wsps[c * 9 + k];
    wsum[k] = s;
  }
}

// ---------------------------------------------------------------------------
// kgy (r11 version + single-g read): 3-way tap-split for occupancy.
// Weights read as wave-uniform global loads (r15 proved LDS staging is
// slower -- the compiler serves these from SGPRs).
// ---------------------------------------------------------------------------
__global__ __launch_bounds__(256) void kgy(
    const float* __restrict__ g, const int* __restrict__ win0,
    const int* __restrict__ win1, const float* __restrict__ feat0,
    const float* __restrict__ vox0, const float* __restrict__ feat1,
    const float* __restrict__ vox1, const float* __restrict__ M0,
    const float* __restrict__ A1, const float* __restrict__ sb,
    const float* __restrict__ wsum, const float* __restrict__ b3,
    float* __restrict__ yp) {
  const int blk = blockIdx.x;
  const int tg = blk % 3;              // tap row group: taps 3tg..3tg+2
  const int pix = (blk / 3) * 256 + threadIdx.x;
  const int b = pix / kHW;
  const int pp = pix - b * kHW;
  const int h = pp / kW;
  const int w = pp - h * kW;
  const float gv = b3[0] + g[pix];
  float y[3];
#pragma unroll
  for (int kk = 0; kk < 3; ++kk)
    y[kk] = wsum[3 * tg + kk] * gv + sb[3 * tg + kk];

  const int w0 = win0[pix];
  if (w0 >= 0) {
    const float4* f0 = (const float4*)(feat0 + ((size_t)b * kN0 + w0) * kC0);
#pragma unroll
    for (int i4 = 0; i4 < 8; ++i4) {
      float4 v = f0[i4];
#pragma unroll
      for (int kk = 0; kk < 3; ++kk) {
        const float* m = M0 + (3 * tg + kk) * 35 + i4 * 4;
        y[kk] += m[0] * v.x + m[1] * v.y + m[2] * v.z + m[3] * v.w;
      }
    }
    const float* v0 = vox0 + ((size_t)b * kN0 + w0) * 3;
#pragma unroll
    for (int i = 0; i < 3; ++i) {
      float v = v0[i];
#pragma unroll
      for (int kk = 0; kk < 3; ++kk)
        y[kk] += M0[(3 * tg + kk) * 35 + kC0 + i] * v;
    }
  }
  const int w1 = win1[pix];
  if (w1 >= 0) {
    const float4* f1 = (const float4*)(feat1 + ((size_t)b * kN1 + w1) * kC1);
#pragma unroll
    for (int i4 = 0; i4 < 16; ++i4) {
      float4 v = f1[i4];
#pragma unroll
      for (int kk = 0; kk < 3; ++kk) {
        const float* m = A1 + (3 * tg + kk) * kCL + i4 * 4;
        y[kk] += m[0] * v.x + m[1] * v.y + m[2] * v.z + m[3] * v.w;
      }
    }
    const float* v1 = vox1 + ((size_t)b * kN1 + w1) * 3;
#pragma unroll
    for (int i = 0; i < 3; ++i) {
      float v = v1[i];
#pragma unroll
      for (int kk = 0; kk < 3; ++kk)
        y[kk] += A1[(3 * tg + kk) * kCL + kC1 + i] * v;
    }
  }
#pragma unroll
  for (int kk = 0; kk < 3; ++kk) {
    yp[((size_t)((3 * tg + kk) * kB + b) * kPH + (h + 1)) * kPW + 4 + w] =
        y[kk];
  }
}

// ---------------------------------------------------------------------------
// fused stencil+sigmoid+multiply, att-in-register:
// block <-> (256-granule chunk, channel HALF). thread <-> granule.
// ---------------------------------------------------------------------------
__global__ __launch_bounds__(256) void kpass2(const float* __restrict__ x_rgb,
                                              const float* __restrict__ yp,
                                              const float* __restrict__ bsp,
                                              float* __restrict__ out) {
  const int bid = blockIdx.x;
  const int q = bid / kChunks;         // channel half 0..1 (uniform/block)
  const int chunk = bid - q * kChunks;
  const int gran = chunk * 256 + threadIdx.x;
  const int b = gran / kHW4;
  const int p4 = gran - b * kHW4;
  const int h = p4 / kW4g;
  const int w4 = p4 - h * kW4g;

  const float bias = bsp[0];
  float4 lg = make_float4(bias, bias, bias, bias);
#pragma unroll
  for (int r = 0; r < 3; ++r) {
    const size_t rowoff = ((size_t)h + r) * kPW + 4 * w4;
    const float* pA = yp + (size_t)((3 * r + 0) * kB + b) * kPlane + rowoff;
    const float* pB = yp + (size_t)((3 * r + 1) * kB + b) * kPlane + rowoff;
    const float* pC = yp + (size_t)((3 * r + 2) * kB + b) * kPlane + rowoff;
    float LA = pA[3];
    float4 a4 = *(const float4*)(pA + 4);
    float4 b4 = *(const float4*)(pB + 4);
    float4 c4 = *(const float4*)(pC + 4);
    float RC = pC[8];
    lg.x += LA + b4.x + c4.y;
    lg.y += a4.x + b4.y + c4.z;
    lg.z += a4.y + b4.z + c4.w;
    lg.w += a4.z + b4.w + RC;
  }
  float4 att;
  att.x = 1.f / (1.f + __expf(-lg.x));
  att.y = 1.f / (1.f + __expf(-lg.y));
  att.z = 1.f / (1.f + __expf(-lg.z));
  att.w = 1.f / (1.f + __expf(-lg.w));

  const vf4* xr = (const vf4*)(x_rgb + (size_t)b * kC * kHW) + p4;
  vf4* op = (vf4*)(out + (size_t)b * kC * kHW) + p4;
#pragma unroll
  for (int cc = 0; cc < 32; ++cc) {
    const int c = q * 32 + cc;
    vf4 x4 = __builtin_nontemporal_load(xr + (size_t)c * kHW4);
    vf4 r4;
    r4.x = x4.x * att.x;
    r4.y = x4.y * att.y;
    r4.z = x4.z * att.z;
    r4.w = x4.w * att.w;
    __builtin_nontemporal_store(r4, op + (size_t)c * kHW4);
  }
}

}  // namespace

extern "C" void kernel_launch(void* const* d_in, const int* in_sizes, int n_in,
                              void* d_out, int out_size, void* d_ws,
                              size_t ws_size, hipStream_t stream) {
  const float* x_rgb = (const float*)d_in[0];
  const float* feat0 = (const float*)d_in[1];
  const float* coor0 = (const float*)d_in[2];
  const float* vox0 = (const float*)d_in[3];
  const float* feat1 = (const float*)d_in[4];
  const float* coor1 = (const float*)d_in[5];
  const float* vox1 = (const float*)d_in[6];
  const float* W0 = (const float*)d_in[7];
  const float* b0 = (const float*)d_in[8];
  const float* W2 = (const float*)d_in[9];
  const float* b2 = (const float*)d_in[10];
  const float* W3 = (const float*)d_in[11];
  const float* b3 = (const float*)d_in[12];
  const float* Wsp = (const float*)d_in[13];
  const float* bsp = (const float*)d_in[14];
  float* out = (float*)d_out;

  // workspace: yp[18*194*648] | g[BHW] | win0[BHW] | win1[BHW] | mats
  float* yp = (float*)d_ws;
  float* g = yp + (size_t)kYPF;
  int* win0 = (int*)(g + (size_t)kBHW);
  int* win1 = win0 + (size_t)kBHW;
  float* M0 = (float*)(win1 + (size_t)kBHW);
  float* A1 = M0 + 9 * 35;
  float* sb = A1 + 9 * kCL;
  float* wsum = sb + 9;

  const int ninit = kBordTot + kWin4;
  kinit<<<(ninit + 255) / 256, 256, 0, stream>>>(yp, (int4*)win0);
  k2<<<kGateB0 + kGateB, 256, 0, stream>>>(coor0, coor1, win0, win1, W0, b0,
                                           W2, b2, Wsp, M0, A1, sb, wsum,
                                           x_rgb, W3, g);
  kgy<<<3 * kBHW / 256, 256, 0, stream>>>(g, win0, win1, feat0, vox0, feat1,
                                          vox1, M0, A1, sb, wsum, b3, yp);
  kpass2<<<2 * kChunks, 256, 0, stream>>>(x_rgb, yp, bsp, out);
}

// Round 17
// 68.799 us; speedup vs baseline: 1.3247x; 1.0417x over previous
//
#include <hip/hip_runtime.h>

namespace {
constexpr int kH = 192, kW = 640, kHW = kH * kW;
constexpr int kW4g = kW / 4;            // 160 granules per row
constexpr int kHW4 = kHW / 4;           // 30720 granules per plane
constexpr int kB = 2, kC = 64;          // batch, image channels
constexpr int kN0 = 40000, kC0 = 32;    // level0 points/channels
constexpr int kN1 = 20000, kC1 = 64;    // level1 points/channels
constexpr int kCL = 67;                 // C1 + 3
constexpr int kBHW = kB * kHW;
// zero-padded y planes: 18 = 9 taps x B, rows H+2, pitch W+8 (interior at +1,+4)
constexpr int kPH = kH + 2, kPW = kW + 8;  // 194 x 648
constexpr int kPW4 = kPW / 4;              // 162
constexpr int kPlane = kPH * kPW;          // 125712
constexpr int kYPF = 18 * kPlane;
constexpr int kWin4 = 2 * kBHW / 4;        // win01 int2 array as int4 pairs
// border float4s per plane: row0 (162) + row193 (162) + 192 rows x {col0,col161}
constexpr int kBord = 162 + 162 + 192 * 2;  // 708
constexpr int kBordTot = 18 * kBord;        // 12744
// K2 block partition: gate FIRST (BW-critical), then scatter, then precomp
constexpr int kGateB = kB * kHW4 / 64;      // 960 gate blocks
constexpr int kScatB0 = kGateB;             // scatter starts at 960
constexpr int kScatB = 469;                 // ceil(120000/256)
constexpr int kPrecB = kScatB0 + kScatB;    // 1429 = precomp block
// kpass2 partition: 240 granule-chunks x 2 channel-halves
constexpr int kChunks = kB * kHW4 / 256;    // 240

typedef float vf4 __attribute__((ext_vector_type(4)));

// ---------------------------------------------------------------------------
// init: zero ONLY the padded-y borders (interior is fully rewritten by kgy
// each replay) and fill the interleaved winner map with -1.
// ---------------------------------------------------------------------------
__global__ __launch_bounds__(256) void kinit(float* __restrict__ yp,
                                             int4* __restrict__ win4) {
  int i = blockIdx.x * 256 + threadIdx.x;
  if (i < kBordTot) {
    int plane = i / kBord, r = i - plane * kBord;
    float4* base = (float4*)(yp + (size_t)plane * kPlane);
    int f4;
    if (r < 162) {
      f4 = r;                                  // row 0
    } else if (r < 324) {
      f4 = 193 * kPW4 + (r - 162);             // row 193
    } else {
      int rr = r - 324;
      int row = 1 + (rr >> 1);
      f4 = row * kPW4 + ((rr & 1) ? (kPW4 - 1) : 0);  // cols 0-3 / 644-647
    }
    base[f4] = make_float4(0.f, 0.f, 0.f, 0.f);
  } else {
    int j = i - kBordTot;
    if (j < kWin4) win4[j] = make_int4(-1, -1, -1, -1);
  }
}

// ---------------------------------------------------------------------------
// K2 (heterogeneous; gate first so the BW-critical 63 MB stream opens at
// dispatch time, scatter+precomp hide in its tail):
//   blocks [0,960): gate -> single summed g plane. Block = 64 granules;
//        256 thr = 64 granules x 4 chunks of 16 ch; LDS-reduce (fixed order).
//   blocks [960,1429): winner scatter into interleaved win01 (int2/pixel,
//        last-write-wins == max index wins)
//   block 1429: LDS-staged fold: b'=W2@b0+b2; A1=Wsp^T@W2; M0=A1@W0;
//        sb_k=Wsp[:,k].b'; wsum_k=sum_c Wsp[c,k]
// ---------------------------------------------------------------------------
__global__ __launch_bounds__(256) void k2(
    const float* __restrict__ coor0, const float* __restrict__ coor1,
    int* __restrict__ win01,
    const float* __restrict__ W0, const float* __restrict__ b0,
    const float* __restrict__ W2, const float* __restrict__ b2,
    const float* __restrict__ Wsp, float* __restrict__ M0,
    float* __restrict__ A1g, float* __restrict__ sb, float* __restrict__ wsum,
    const float* __restrict__ x_rgb, const float* __restrict__ W3,
    float* __restrict__ g) {
  __shared__ float W2s[kCL * kCL];
  __shared__ float W0s[kCL * 35];
  __shared__ float Wsps[kCL * 9];
  __shared__ float A1s[9 * kCL];
  __shared__ float bps[kCL];
  const int bid = blockIdx.x;
  const int t = threadIdx.x;
  if (bid < kGateB) {  // ---- gate ----
    __shared__ float4 part[4][64];
    const int gg = t & 63, q = t >> 6;
    const int gran = bid * 64 + gg;
    const int b = gran / kHW4;
    const int p4 = gran - b * kHW4;
    const float4* xr = (const float4*)(x_rgb + (size_t)b * kC * kHW) + p4;
    float4 acc = make_float4(0.f, 0.f, 0.f, 0.f);
#pragma unroll
    for (int cc = 0; cc < 16; ++cc) {
      const int c = q * 16 + cc;
      float wv = W3[c];
      float4 x4 = xr[(size_t)c * kHW4];
      acc.x += wv * x4.x;
      acc.y += wv * x4.y;
      acc.z += wv * x4.z;
      acc.w += wv * x4.w;
    }
    part[q][gg] = acc;
    __syncthreads();
    if (t < 64) {
      float4 p0 = part[0][t], p1 = part[1][t], p2 = part[2][t],
             p3 = part[3][t];
      float4 s;
      s.x = p0.x + p1.x + p2.x + p3.x;
      s.y = p0.y + p1.y + p2.y + p3.y;
      s.z = p0.z + p1.z + p2.z + p3.z;
      s.w = p0.w + p1.w + p2.w + p3.w;
      ((float4*)g)[bid * 64 + t] = s;
    }
    return;
  }
  if (bid < kPrecB) {  // ---- scatter ----
    int idx = (bid - kScatB0) * 256 + t;
    const float* coor;
    int lvl, N;
    if (idx < kB * kN0) {
      coor = coor0; lvl = 0; N = kN0;
    } else {
      idx -= kB * kN0;
      if (idx >= kB * kN1) return;
      coor = coor1; lvl = 1; N = kN1;
    }
    int b = idx / N;
    float u = coor[(size_t)idx * 2 + 0];
    float v = coor[(size_t)idx * 2 + 1];
    u = fminf(fmaxf(u, 0.f), 1.f);
    v = fminf(fmaxf(v, 0.f), 1.f);
    int r = (int)(v * (float)kH);  // row from coor[:,1]
    int c = (int)(u * (float)kW);  // col from coor[:,0]
    if (r < kH && c < kW) {
      int n = idx - b * N;
      atomicMax(&win01[2 * (b * kHW + r * kW + c) + lvl], n);
    }
    return;
  }
  // ---- precomp (block 1429, LDS-staged) ----
  for (int i = t; i < kCL * kCL; i += 256) W2s[i] = W2[i];
  for (int i = t; i < kCL * 35; i += 256) W0s[i] = W0[i];
  for (int i = t; i < kCL * 9; i += 256) Wsps[i] = Wsp[i];
  __syncthreads();
  if (t < kCL) {
    float s = b2[t];
    for (int j = 0; j < kCL; ++j) s += W2s[t * kCL + j] * b0[j];
    bps[t] = s;
  }
  for (int idx = t; idx < 9 * kCL; idx += 256) {
    int k = idx / kCL, j = idx - k * kCL;
    float s = 0.f;
    for (int c = 0; c < kCL; ++c) s += Wsps[c * 9 + k] * W2s[c * kCL + j];
    A1s[idx] = s;
    A1g[idx] = s;
  }
  __syncthreads();
  for (int idx = t; idx < 9 * 35; idx += 256) {
    int k = idx / 35, i = idx - k * 35;
    float s = 0.f;
    for (int j = 0; j < kCL; ++j) s += A1s[k * kCL + j] * W0s[j * 35 + i];
    M0[idx] = s;
  }
  if (t < 9) {
    float s = 0.f;
    for (int c = 0; c < kCL; ++c) s += Wsps[c * 9 + t] * bps[c];
    sb[t] = s;
  } else if (t >= 16 && t < 25) {
    int k = t - 16;
    float s = 0.f;
    for (int c = 0; c < kCL; ++c) s += Wsps[c * 9 + k];
    wsum[k] = s;
  }
}

// ---------------------------------------------------------------------------
// kgy: 3-way tap-split for occupancy; winners read as one int2/pixel.
// Weights read as wave-uniform global loads (r15 proved LDS staging is
// slower -- the compiler serves these from SGPRs).
// ---------------------------------------------------------------------------
__global__ __launch_bounds__(256) void kgy(
    const float* __restrict__ g, const int2* __restrict__ win01,
    const float* __restrict__ feat0, const float* __restrict__ vox0,
    const float* __restrict__ feat1, const float* __restrict__ vox1,
    const float* __restrict__ M0, const float* __restrict__ A1,
    const float* __restrict__ sb, const float* __restrict__ wsum,
    const float* __restrict__ b3, float* __restrict__ yp) {
  const int blk = blockIdx.x;
  const int tg = blk % 3;              // tap row group: taps 3tg..3tg+2
  const int pix = (blk / 3) * 256 + threadIdx.x;
  const int b = pix / kHW;
  const int pp = pix - b * kHW;
  const int h = pp / kW;
  const int w = pp - h * kW;
  const float gv = b3[0] + g[pix];
  float y[3];
#pragma unroll
  for (int kk = 0; kk < 3; ++kk)
    y[kk] = wsum[3 * tg + kk] * gv + sb[3 * tg + kk];

  const int2 wv2 = win01[pix];
  const int w0 = wv2.x;
  if (w0 >= 0) {
    const float4* f0 = (const float4*)(feat0 + ((size_t)b * kN0 + w0) * kC0);
#pragma unroll
    for (int i4 = 0; i4 < 8; ++i4) {
      float4 v = f0[i4];
#pragma unroll
      for (int kk = 0; kk < 3; ++kk) {
        const float* m = M0 + (3 * tg + kk) * 35 + i4 * 4;
        y[kk] += m[0] * v.x + m[1] * v.y + m[2] * v.z + m[3] * v.w;
      }
    }
    const float* v0 = vox0 + ((size_t)b * kN0 + w0) * 3;
#pragma unroll
    for (int i = 0; i < 3; ++i) {
      float v = v0[i];
#pragma unroll
      for (int kk = 0; kk < 3; ++kk)
        y[kk] += M0[(3 * tg + kk) * 35 + kC0 + i] * v;
    }
  }
  const int w1 = wv2.y;
  if (w1 >= 0) {
    const float4* f1 = (const float4*)(feat1 + ((size_t)b * kN1 + w1) * kC1);
#pragma unroll
    for (int i4 = 0; i4 < 16; ++i4) {
      float4 v = f1[i4];
#pragma unroll
      for (int kk = 0; kk < 3; ++kk) {
        const float* m = A1 + (3 * tg + kk) * kCL + i4 * 4;
        y[kk] += m[0] * v.x + m[1] * v.y + m[2] * v.z + m[3] * v.w;
      }
    }
    const float* v1 = vox1 + ((size_t)b * kN1 + w1) * 3;
#pragma unroll
    for (int i = 0; i < 3; ++i) {
      float v = v1[i];
#pragma unroll
      for (int kk = 0; kk < 3; ++kk)
        y[kk] += A1[(3 * tg + kk) * kCL + kC1 + i] * v;
    }
  }
#pragma unroll
  for (int kk = 0; kk < 3; ++kk) {
    yp[((size_t)((3 * tg + kk) * kB + b) * kPH + (h + 1)) * kPW + 4 + w] =
        y[kk];
  }
}

// ---------------------------------------------------------------------------
// fused stencil+sigmoid+multiply, att-in-register:
// block <-> (256-granule chunk, channel HALF). thread <-> granule.
// x loads are PLAIN (cached -- x is L3-resident after k2's gate read);
// out stores nontemporal (never re-read).
// ---------------------------------------------------------------------------
__global__ __launch_bounds__(256) void kpass2(const float* __restrict__ x_rgb,
                                              const float* __restrict__ yp,
                                              const float* __restrict__ bsp,
                                              float* __restrict__ out) {
  const int bid = blockIdx.x;
  const int q = bid / kChunks;         // channel half 0..1 (uniform/block)
  const int chunk = bid - q * kChunks;
  const int gran = chunk * 256 + threadIdx.x;
  const int b = gran / kHW4;
  const int p4 = gran - b * kHW4;
  const int h = p4 / kW4g;
  const int w4 = p4 - h * kW4g;

  const float bias = bsp[0];
  float4 lg = make_float4(bias, bias, bias, bias);
#pragma unroll
  for (int r = 0; r < 3; ++r) {
    const size_t rowoff = ((size_t)h + r) * kPW + 4 * w4;
    const float* pA = yp + (size_t)((3 * r + 0) * kB + b) * kPlane + rowoff;
    const float* pB = yp + (size_t)((3 * r + 1) * kB + b) * kPlane + rowoff;
    const float* pC = yp + (size_t)((3 * r + 2) * kB + b) * kPlane + rowoff;
    float LA = pA[3];
    float4 a4 = *(const float4*)(pA + 4);
    float4 b4 = *(const float4*)(pB + 4);
    float4 c4 = *(const float4*)(pC + 4);
    float RC = pC[8];
    lg.x += LA + b4.x + c4.y;
    lg.y += a4.x + b4.y + c4.z;
    lg.z += a4.y + b4.z + c4.w;
    lg.w += a4.z + b4.w + RC;
  }
  float4 att;
  att.x = 1.f / (1.f + __expf(-lg.x));
  att.y = 1.f / (1.f + __expf(-lg.y));
  att.z = 1.f / (1.f + __expf(-lg.z));
  att.w = 1.f / (1.f + __expf(-lg.w));

  const float4* xr = (const float4*)(x_rgb + (size_t)b * kC * kHW) + p4;
  vf4* op = (vf4*)(out + (size_t)b * kC * kHW) + p4;
#pragma unroll
  for (int cc = 0; cc < 32; ++cc) {
    const int c = q * 32 + cc;
    float4 x4 = xr[(size_t)c * kHW4];
    vf4 r4;
    r4.x = x4.x * att.x;
    r4.y = x4.y * att.y;
    r4.z = x4.z * att.z;
    r4.w = x4.w * att.w;
    __builtin_nontemporal_store(r4, op + (size_t)c * kHW4);
  }
}

}  // namespace

extern "C" void kernel_launch(void* const* d_in, const int* in_sizes, int n_in,
                              void* d_out, int out_size, void* d_ws,
                              size_t ws_size, hipStream_t stream) {
  const float* x_rgb = (const float*)d_in[0];
  const float* feat0 = (const float*)d_in[1];
  const float* coor0 = (const float*)d_in[2];
  const float* vox0 = (const float*)d_in[3];
  const float* feat1 = (const float*)d_in[4];
  const float* coor1 = (const float*)d_in[5];
  const float* vox1 = (const float*)d_in[6];
  const float* W0 = (const float*)d_in[7];
  const float* b0 = (const float*)d_in[8];
  const float* W2 = (const float*)d_in[9];
  const float* b2 = (const float*)d_in[10];
  const float* W3 = (const float*)d_in[11];
  const float* b3 = (const float*)d_in[12];
  const float* Wsp = (const float*)d_in[13];
  const float* bsp = (const float*)d_in[14];
  float* out = (float*)d_out;

  // workspace: yp[18*194*648] | g[BHW] | win01[2*BHW] | M0 | A1 | sb | wsum
  float* yp = (float*)d_ws;
  float* g = yp + (size_t)kYPF;
  int* win01 = (int*)(g + (size_t)kBHW);
  float* M0 = (float*)(win01 + (size_t)2 * kBHW);
  float* A1 = M0 + 9 * 35;
  float* sb = A1 + 9 * kCL;
  float* wsum = sb + 9;

  const int ninit = kBordTot + kWin4;
  kinit<<<(ninit + 255) / 256, 256, 0, stream>>>(yp, (int4*)win01);
  k2<<<kPrecB + 1, 256, 0, stream>>>(coor0, coor1, win01, W0, b0, W2, b2, Wsp,
                                     M0, A1, sb, wsum, x_rgb, W3, g);
  kgy<<<3 * kBHW / 256, 256, 0, stream>>>(g, (const int2*)win01, feat0, vox0,
                                          feat1, vox1, M0, A1, sb, wsum, b3,
                                          yp);
  kpass2<<<2 * kChunks, 256, 0, stream>>>(x_rgb, yp, bsp, out);
}